// Round 2
// baseline (294.318 us; speedup 1.0000x reference)
//
#include <hip/hip_runtime.h>

typedef unsigned int uint32;
typedef unsigned long long uint64;

#define BLOCK 256
#define IPT 16                  // rows per thread
#define CHUNK (BLOCK * IPT)     // 4096 rows per block
#define SCORE_THR 0.35f

// Block-wide reduce of two uint32 values (one barrier). Returns via refs; all
// threads get the result.
__device__ inline void block_reduce2(uint32& a, uint32& b) {
    int tid = threadIdx.x;
    int wave = tid >> 6, lane = tid & 63;
    for (int off = 32; off > 0; off >>= 1) {
        a += __shfl_down(a, off, 64);
        b += __shfl_down(b, off, 64);
    }
    __shared__ uint32 ra[BLOCK / 64], rb[BLOCK / 64];
    if (lane == 0) { ra[wave] = a; rb[wave] = b; }
    __syncthreads();
    uint32 sa = 0, sb = 0;
    for (int w = 0; w < BLOCK / 64; ++w) { sa += ra[w]; sb += rb[w]; }
    a = sa; b = sb;
}

// ---------------- Kernel 1: per-block mask counts (float4 loads) -----------
__global__ void count_kernel(const float* __restrict__ det,
                             uint32* __restrict__ c0, uint32* __restrict__ c1,
                             int R) {
    int tid = threadIdx.x;
    long long base = (long long)blockIdx.x * CHUNK;
    uint32 cnt0 = 0, cnt1 = 0;

    if (base + CHUNK <= R) {
        // fast path: 2 rows per thread per iteration via 3 float4 loads
        const float4* d4 = (const float4*)det + base * 6 / 4;
        for (int it = 0; it < IPT / 2; ++it) {
            const float4* p = d4 + (long long)it * (BLOCK * 3) + 3 * tid;
            float4 f0 = p[0], f1 = p[1], f2 = p[2];
            bool mA1 = (f1.y >= SCORE_THR);
            bool mA0 = mA1 && (f0.x == 0.0f);
            bool mB1 = (f2.w >= SCORE_THR);
            bool mB0 = mB1 && (f1.z == 0.0f);
            cnt1 += (mA1 ? 1u : 0u) + (mB1 ? 1u : 0u);
            cnt0 += (mA0 ? 1u : 0u) + (mB0 ? 1u : 0u);
        }
    } else {
        for (int i = 0; i < IPT; ++i) {
            long long row = base + (long long)i * BLOCK + tid;
            if (row < R) {
                float c = det[row * 6 + 0];
                float s = det[row * 6 + 5];
                bool m1 = (s >= SCORE_THR);
                bool m0 = m1 && (c == 0.0f);
                cnt1 += m1 ? 1u : 0u;
                cnt0 += m0 ? 1u : 0u;
            }
        }
    }

    block_reduce2(cnt0, cnt1);
    if (tid == 0) { c0[blockIdx.x] = cnt0; c1[blockIdx.x] = cnt1; }
}

// ---------------- Kernel 2: prefix + stable scatter + tail zero ------------
__global__ void scatter_zero_kernel(const float* __restrict__ det,
                                    float* __restrict__ rois, float* __restrict__ roisf,
                                    const uint32* __restrict__ c0, const uint32* __restrict__ c1,
                                    float* __restrict__ out_n,
                                    int R, int NB) {
    int tid = threadIdx.x;
    int wave = tid >> 6, lane = tid & 63;
    int bid = blockIdx.x;

    // ---- Phase 1: my exclusive block offset + grand totals (from L2) ----
    uint32 pre0 = 0, pre1 = 0, tot0 = 0, tot1 = 0;
    for (int j = tid; j < NB; j += BLOCK) {
        uint32 a = c0[j], b = c1[j];
        tot0 += a; tot1 += b;
        if (j < bid) { pre0 += a; pre1 += b; }
    }
    // reduce 4 values across block
    for (int off = 32; off > 0; off >>= 1) {
        pre0 += __shfl_down(pre0, off, 64);
        pre1 += __shfl_down(pre1, off, 64);
        tot0 += __shfl_down(tot0, off, 64);
        tot1 += __shfl_down(tot1, off, 64);
    }
    __shared__ uint32 lp0[4], lp1[4], lt0[4], lt1[4];
    if (lane == 0) { lp0[wave] = pre0; lp1[wave] = pre1; lt0[wave] = tot0; lt1[wave] = tot1; }
    __syncthreads();
    pre0 = lp0[0] + lp0[1] + lp0[2] + lp0[3];
    pre1 = lp1[0] + lp1[1] + lp1[2] + lp1[3];
    tot0 = lt0[0] + lt0[1] + lt0[2] + lt0[3];
    tot1 = lt1[0] + lt1[1] + lt1[2] + lt1[3];

    if (bid == 0 && tid == 0) {
        out_n[0] = (float)tot0;   // n
        out_n[1] = (float)tot1;   // n_full
    }

    // ---- Phase 2: stable scatter, 1 barrier per iteration ----
    __shared__ uint32 wc0[2][4], wc1[2][4];
    uint32 run0 = pre0, run1 = pre1;      // uniform across block
    long long base = (long long)bid * CHUNK;
    uint64 ltmask = (1ull << lane) - 1ull;

    if (base + CHUNK <= R) {
        const float4* d4 = (const float4*)det + base * 6 / 4;
        for (int it = 0; it < IPT / 2; ++it) {
            const float4* p = d4 + (long long)it * (BLOCK * 3) + 3 * tid;
            float4 f0 = p[0], f1 = p[1], f2 = p[2];
            // row A = {f0.x, f0.y, f0.z, f0.w, f1.x, f1.y}
            // row B = {f1.z, f1.w, f2.x, f2.y, f2.z, f2.w}
            bool mA1 = (f1.y >= SCORE_THR);
            bool mA0 = mA1 && (f0.x == 0.0f);
            bool mB1 = (f2.w >= SCORE_THR);
            bool mB0 = mB1 && (f1.z == 0.0f);

            uint64 bA0 = __ballot(mA0), bA1 = __ballot(mA1);
            uint64 bB0 = __ballot(mB0), bB1 = __ballot(mB1);

            int buf = it & 1;
            if (lane == 0) {
                wc0[buf][wave] = (uint32)(__popcll(bA0) + __popcll(bB0));
                wc1[buf][wave] = (uint32)(__popcll(bA1) + __popcll(bB1));
            }
            __syncthreads();
            uint32 wp0 = 0, wp1 = 0, bt0 = 0, bt1 = 0;
            for (int w = 0; w < 4; ++w) {
                uint32 a = wc0[buf][w], b = wc1[buf][w];
                bt0 += a; bt1 += b;
                if (w < wave) { wp0 += a; wp1 += b; }
            }
            uint32 rA0 = run0 + wp0 + (uint32)(__popcll(bA0 & ltmask) + __popcll(bB0 & ltmask));
            uint32 rB0 = rA0 + (mA0 ? 1u : 0u);
            uint32 rA1 = run1 + wp1 + (uint32)(__popcll(bA1 & ltmask) + __popcll(bB1 & ltmask));
            uint32 rB1 = rA1 + (mA1 ? 1u : 0u);

            if (mA0) {
                float* q = rois + (long long)rA0 * 5;
                q[0] = 0.0f; q[1] = f0.y; q[2] = f0.z; q[3] = f0.w; q[4] = f1.x;
            }
            if (mB0) {
                float* q = rois + (long long)rB0 * 5;
                q[0] = 0.0f; q[1] = f1.w; q[2] = f2.x; q[3] = f2.y; q[4] = f2.z;
            }
            if (mA1) {
                float* q = roisf + (long long)rA1 * 6;
                q[0] = f0.x; q[1] = f0.y; q[2] = f0.z; q[3] = f0.w; q[4] = f1.x; q[5] = f1.y;
            }
            if (mB1) {
                float* q = roisf + (long long)rB1 * 6;
                q[0] = f1.z; q[1] = f1.w; q[2] = f2.x; q[3] = f2.y; q[4] = f2.z; q[5] = f2.w;
            }
            run0 += bt0; run1 += bt1;
        }
    } else {
        // slow path (remainder block) — scalar, 1 row per thread per iter
        for (int i = 0; i < IPT; ++i) {
            long long row = base + (long long)i * BLOCK + tid;
            bool m0 = false, m1 = false;
            float d0 = 0, d1 = 0, d2 = 0, d3 = 0, d4v = 0, d5 = 0;
            if (row < R) {
                const float* pp = det + row * 6;
                d0 = pp[0]; d1 = pp[1]; d2 = pp[2]; d3 = pp[3]; d4v = pp[4]; d5 = pp[5];
                m1 = (d5 >= SCORE_THR);
                m0 = m1 && (d0 == 0.0f);
            }
            uint64 b0 = __ballot(m0), b1 = __ballot(m1);
            int buf = i & 1;
            if (lane == 0) {
                wc0[buf][wave] = (uint32)__popcll(b0);
                wc1[buf][wave] = (uint32)__popcll(b1);
            }
            __syncthreads();
            uint32 wp0 = 0, wp1 = 0, bt0 = 0, bt1 = 0;
            for (int w = 0; w < 4; ++w) {
                uint32 a = wc0[buf][w], b = wc1[buf][w];
                bt0 += a; bt1 += b;
                if (w < wave) { wp0 += a; wp1 += b; }
            }
            if (m0) {
                uint32 pos = run0 + wp0 + (uint32)__popcll(b0 & ltmask);
                float* q = rois + (long long)pos * 5;
                q[0] = 0.0f; q[1] = d1; q[2] = d2; q[3] = d3; q[4] = d4v;
            }
            if (m1) {
                uint32 pos = run1 + wp1 + (uint32)__popcll(b1 & ltmask);
                float* q = roisf + (long long)pos * 6;
                q[0] = d0; q[1] = d1; q[2] = d2; q[3] = d3; q[4] = d4v; q[5] = d5;
            }
            run0 += bt0; run1 += bt1;
        }
    }

    // ---- Phase 3: zero-fill tails (disjoint from all scatter writes) ----
    long long z0 = (long long)R * 5 - (long long)tot0 * 5;
    long long z1 = (long long)R * 6 - (long long)tot1 * 6;
    long long total = z0 + z1;
    float* zb0 = rois + (long long)tot0 * 5;
    float* zb1 = roisf + (long long)tot1 * 6;
    long long idx = (long long)bid * BLOCK + tid;
    long long stride = (long long)NB * BLOCK;
    for (long long k = idx; k < total; k += stride) {
        if (k < z0) zb0[k] = 0.0f;
        else        zb1[k - z0] = 0.0f;
    }
}

extern "C" void kernel_launch(void* const* d_in, const int* in_sizes, int n_in,
                              void* d_out, int out_size, void* d_ws, size_t ws_size,
                              hipStream_t stream) {
    const float* det = (const float*)d_in[0];
    float* out = (float*)d_out;
    int R = in_sizes[0] / 6;
    int NB = (R + CHUNK - 1) / CHUNK;

    uint32* ws = (uint32*)d_ws;
    uint32* c0 = ws;
    uint32* c1 = ws + NB;

    float* rois  = out;                          // (R,5)
    float* roisf = out + (long long)R * 5;       // (R,6)
    float* nout  = out + (long long)R * 11;      // n, n_full

    count_kernel<<<NB, BLOCK, 0, stream>>>(det, c0, c1, R);
    scatter_zero_kernel<<<NB, BLOCK, 0, stream>>>(det, rois, roisf, c0, c1, nout, R, NB);
}

// Round 3
// 286.865 us; speedup vs baseline: 1.0260x; 1.0260x over previous
//
#include <hip/hip_runtime.h>

typedef unsigned int uint32;
typedef unsigned long long uint64;

#define BLOCK 256
#define IPT 16                  // rows per thread
#define CHUNK (BLOCK * IPT)     // 4096 rows per block
#define RPI 512                 // rows per iteration (2 per thread)
#define SCORE_THR 0.35f

// ---------------- Kernel 1: per-block mask counts (float4 loads) -----------
__global__ void count_kernel(const float* __restrict__ det,
                             uint32* __restrict__ c0, uint32* __restrict__ c1,
                             int R) {
    int tid = threadIdx.x;
    int wave = tid >> 6, lane = tid & 63;
    long long base = (long long)blockIdx.x * CHUNK;
    uint32 cnt0 = 0, cnt1 = 0;

    if (base + CHUNK <= R) {
        const float4* d4 = (const float4*)det + base * 6 / 4;
        for (int it = 0; it < IPT / 2; ++it) {
            const float4* p = d4 + (long long)it * (BLOCK * 3) + 3 * tid;
            float4 f0 = p[0], f1 = p[1], f2 = p[2];
            bool mA1 = (f1.y >= SCORE_THR);
            bool mA0 = mA1 && (f0.x == 0.0f);
            bool mB1 = (f2.w >= SCORE_THR);
            bool mB0 = mB1 && (f1.z == 0.0f);
            cnt1 += (mA1 ? 1u : 0u) + (mB1 ? 1u : 0u);
            cnt0 += (mA0 ? 1u : 0u) + (mB0 ? 1u : 0u);
        }
    } else {
        for (int i = 0; i < IPT; ++i) {
            long long row = base + (long long)i * BLOCK + tid;
            if (row < R) {
                float c = det[row * 6 + 0];
                float s = det[row * 6 + 5];
                bool m1 = (s >= SCORE_THR);
                bool m0 = m1 && (c == 0.0f);
                cnt1 += m1 ? 1u : 0u;
                cnt0 += m0 ? 1u : 0u;
            }
        }
    }

    for (int off = 32; off > 0; off >>= 1) {
        cnt0 += __shfl_down(cnt0, off, 64);
        cnt1 += __shfl_down(cnt1, off, 64);
    }
    __shared__ uint32 ra[4], rb[4];
    if (lane == 0) { ra[wave] = cnt0; rb[wave] = cnt1; }
    __syncthreads();
    if (tid == 0) {
        c0[blockIdx.x] = ra[0] + ra[1] + ra[2] + ra[3];
        c1[blockIdx.x] = rb[0] + rb[1] + rb[2] + rb[3];
    }
}

// grid-stride zero of n floats starting at p, vectorized float4 body
__device__ inline void zero_region(float* p, long long n,
                                   long long gtid, long long gstride) {
    if (n <= 0) return;
    long long head = ((4 - (((size_t)p >> 2) & 3)) & 3);
    if (head > n) head = n;
    if (gtid < head) p[gtid] = 0.0f;
    long long n4 = (n - head) >> 2;
    float4* b = (float4*)(p + head);
    float4 z4 = make_float4(0.f, 0.f, 0.f, 0.f);
    for (long long k = gtid; k < n4; k += gstride) b[k] = z4;
    long long done = head + (n4 << 2);
    long long rem = n - done;
    if (gtid < rem) p[done + gtid] = 0.0f;
}

// ---------------- Kernel 2: prefix + LDS-staged stable scatter + zero ------
__global__ void scatter_zero_kernel(const float* __restrict__ det,
                                    float* __restrict__ rois, float* __restrict__ roisf,
                                    const uint32* __restrict__ c0, const uint32* __restrict__ c1,
                                    float* __restrict__ out_n,
                                    int R, int NB) {
    int tid = threadIdx.x;
    int wave = tid >> 6, lane = tid & 63;
    int bid = blockIdx.x;

    // ---- Phase 1: exclusive block offset + grand totals (L2 reads) ----
    uint32 pre0 = 0, pre1 = 0, tot0 = 0, tot1 = 0;
    for (int j = tid; j < NB; j += BLOCK) {
        uint32 a = c0[j], b = c1[j];
        tot0 += a; tot1 += b;
        if (j < bid) { pre0 += a; pre1 += b; }
    }
    for (int off = 32; off > 0; off >>= 1) {
        pre0 += __shfl_down(pre0, off, 64);
        pre1 += __shfl_down(pre1, off, 64);
        tot0 += __shfl_down(tot0, off, 64);
        tot1 += __shfl_down(tot1, off, 64);
    }
    __shared__ uint32 lp0[4], lp1[4], lt0[4], lt1[4];
    if (lane == 0) { lp0[wave] = pre0; lp1[wave] = pre1; lt0[wave] = tot0; lt1[wave] = tot1; }
    __syncthreads();
    pre0 = lp0[0] + lp0[1] + lp0[2] + lp0[3];
    pre1 = lp1[0] + lp1[1] + lp1[2] + lp1[3];
    tot0 = lt0[0] + lt0[1] + lt0[2] + lt0[3];
    tot1 = lt1[0] + lt1[1] + lt1[2] + lt1[3];

    if (bid == 0 && tid == 0) {
        out_n[0] = (float)tot0;   // n
        out_n[1] = (float)tot1;   // n_full
    }

    // ---- Phase 2: stable scatter via LDS staging, dense coalesced writes --
    __shared__ uint32 wc0[2][4], wc1[2][4];
    __shared__ float st0[2][RPI * 5];   // 2 x 10 KB
    __shared__ float st1[2][RPI * 6];   // 2 x 12 KB
    uint32 run0 = pre0, run1 = pre1;    // uniform across block
    long long base = (long long)bid * CHUNK;
    uint64 ltmask = (1ull << lane) - 1ull;

    if (base + CHUNK <= R) {
        const float4* d4 = (const float4*)det + base * 6 / 4;
        for (int it = 0; it < IPT / 2; ++it) {
            int buf = it & 1;
            const float4* p = d4 + (long long)it * (BLOCK * 3) + 3 * tid;
            float4 f0 = p[0], f1 = p[1], f2 = p[2];
            // row A = {f0.x,f0.y,f0.z,f0.w,f1.x,f1.y}, row B = {f1.z,f1.w,f2.x,f2.y,f2.z,f2.w}
            bool mA1 = (f1.y >= SCORE_THR);
            bool mA0 = mA1 && (f0.x == 0.0f);
            bool mB1 = (f2.w >= SCORE_THR);
            bool mB0 = mB1 && (f1.z == 0.0f);

            uint64 bA0 = __ballot(mA0), bA1 = __ballot(mA1);
            uint64 bB0 = __ballot(mB0), bB1 = __ballot(mB1);

            if (lane == 0) {
                wc0[buf][wave] = (uint32)(__popcll(bA0) + __popcll(bB0));
                wc1[buf][wave] = (uint32)(__popcll(bA1) + __popcll(bB1));
            }
            __syncthreads();   // barrier 1: counts ready
            uint32 wp0 = 0, wp1 = 0, bt0 = 0, bt1 = 0;
            for (int w = 0; w < 4; ++w) {
                uint32 a = wc0[buf][w], b = wc1[buf][w];
                bt0 += a; bt1 += b;
                if (w < wave) { wp0 += a; wp1 += b; }
            }
            // local (iteration) compact ranks
            uint32 lA0 = wp0 + (uint32)(__popcll(bA0 & ltmask) + __popcll(bB0 & ltmask));
            uint32 lB0 = lA0 + (mA0 ? 1u : 0u);
            uint32 lA1 = wp1 + (uint32)(__popcll(bA1 & ltmask) + __popcll(bB1 & ltmask));
            uint32 lB1 = lA1 + (mA1 ? 1u : 0u);

            if (mA0) {
                float* s = &st0[buf][lA0 * 5];
                s[0] = 0.0f; s[1] = f0.y; s[2] = f0.z; s[3] = f0.w; s[4] = f1.x;
            }
            if (mB0) {
                float* s = &st0[buf][lB0 * 5];
                s[0] = 0.0f; s[1] = f1.w; s[2] = f2.x; s[3] = f2.y; s[4] = f2.z;
            }
            if (mA1) {
                float* s = &st1[buf][lA1 * 6];
                s[0] = f0.x; s[1] = f0.y; s[2] = f0.z; s[3] = f0.w; s[4] = f1.x; s[5] = f1.y;
            }
            if (mB1) {
                float* s = &st1[buf][lB1 * 6];
                s[0] = f1.z; s[1] = f1.w; s[2] = f2.x; s[3] = f2.y; s[4] = f2.z; s[5] = f2.w;
            }
            __syncthreads();   // barrier 2: staging complete

            // dense, coalesced copy-out (consecutive dwords per wave)
            uint32 N0 = bt0 * 5, N1 = bt1 * 6;
            float* g0 = rois + (long long)run0 * 5;
            float* g1 = roisf + (long long)run1 * 6;
            for (uint32 j = tid; j < N0; j += BLOCK) g0[j] = st0[buf][j];
            for (uint32 j = tid; j < N1; j += BLOCK) g1[j] = st1[buf][j];
            run0 += bt0; run1 += bt1;
            // double-buffering makes a third barrier unnecessary
        }
    } else {
        // remainder block (not hit when R % CHUNK == 0): direct scalar scatter
        for (int i = 0; i < IPT; ++i) {
            long long row = base + (long long)i * BLOCK + tid;
            bool m0 = false, m1 = false;
            float d0 = 0, d1 = 0, d2 = 0, d3 = 0, d4v = 0, d5 = 0;
            if (row < R) {
                const float* pp = det + row * 6;
                d0 = pp[0]; d1 = pp[1]; d2 = pp[2]; d3 = pp[3]; d4v = pp[4]; d5 = pp[5];
                m1 = (d5 >= SCORE_THR);
                m0 = m1 && (d0 == 0.0f);
            }
            uint64 b0 = __ballot(m0), b1 = __ballot(m1);
            int buf = i & 1;
            if (lane == 0) {
                wc0[buf][wave] = (uint32)__popcll(b0);
                wc1[buf][wave] = (uint32)__popcll(b1);
            }
            __syncthreads();
            uint32 wp0 = 0, wp1 = 0, bt0 = 0, bt1 = 0;
            for (int w = 0; w < 4; ++w) {
                uint32 a = wc0[buf][w], b = wc1[buf][w];
                bt0 += a; bt1 += b;
                if (w < wave) { wp0 += a; wp1 += b; }
            }
            if (m0) {
                uint32 pos = run0 + wp0 + (uint32)__popcll(b0 & ltmask);
                float* q = rois + (long long)pos * 5;
                q[0] = 0.0f; q[1] = d1; q[2] = d2; q[3] = d3; q[4] = d4v;
            }
            if (m1) {
                uint32 pos = run1 + wp1 + (uint32)__popcll(b1 & ltmask);
                float* q = roisf + (long long)pos * 6;
                q[0] = d0; q[1] = d1; q[2] = d2; q[3] = d3; q[4] = d4v; q[5] = d5;
            }
            run0 += bt0; run1 += bt1;
            __syncthreads();
        }
    }

    // ---- Phase 3: zero-fill tails (disjoint from all scatter writes) ----
    long long gtid = (long long)bid * BLOCK + tid;
    long long gstride = (long long)NB * BLOCK;
    zero_region(rois + (long long)tot0 * 5, (long long)(R - (long long)tot0) * 5,
                gtid, gstride);
    zero_region(roisf + (long long)tot1 * 6, (long long)(R - (long long)tot1) * 6,
                gtid, gstride);
}

extern "C" void kernel_launch(void* const* d_in, const int* in_sizes, int n_in,
                              void* d_out, int out_size, void* d_ws, size_t ws_size,
                              hipStream_t stream) {
    const float* det = (const float*)d_in[0];
    float* out = (float*)d_out;
    int R = in_sizes[0] / 6;
    int NB = (R + CHUNK - 1) / CHUNK;

    uint32* ws = (uint32*)d_ws;
    uint32* c0 = ws;
    uint32* c1 = ws + NB;

    float* rois  = out;                          // (R,5)
    float* roisf = out + (long long)R * 5;       // (R,6)
    float* nout  = out + (long long)R * 11;      // n, n_full

    count_kernel<<<NB, BLOCK, 0, stream>>>(det, c0, c1, R);
    scatter_zero_kernel<<<NB, BLOCK, 0, stream>>>(det, rois, roisf, c0, c1, nout, R, NB);
}